// Round 4
// baseline (1325.555 us; speedup 1.0000x reference)
//
#include <hip/hip_runtime.h>
#include <hip/hip_bf16.h>

// Problem constants
#define TQn 1024
#define Bn  16
#define Hn  1024
#define Sn  4096

#define BM 128   // s-tile
#define BN 128   // t-tile

typedef _Float16 f16x8 __attribute__((ext_vector_type(8)));
typedef float    f32x4 __attribute__((ext_vector_type(4)));

#if defined(__has_builtin)
#if __has_builtin(__builtin_amdgcn_global_load_lds)
#define HAVE_GLDS 1
#else
#define HAVE_GLDS 0
#endif
#else
#define HAVE_GLDS 0
#endif

__device__ __forceinline__ void cvt_split(const f32x4& v0, const f32x4& v1,
                                          f16x8& hi, f16x8& lo) {
#pragma unroll
  for (int e = 0; e < 4; ++e) {
    _Float16 h = (_Float16)v0[e];
    hi[e] = h;
    lo[e] = (_Float16)(v0[e] - (float)h);
  }
#pragma unroll
  for (int e = 0; e < 4; ++e) {
    _Float16 h = (_Float16)v1[e];
    hi[4 + e] = h;
    lo[4 + e] = (_Float16)(v1[e] - (float)h);
  }
}

// ============================ FAST PATH ============================

// pre-pass: f32 -> (hi,lo) f16 planes, 8 elems/thread/iter, BW-bound
__global__ __launch_bounds__(256)
void cvt_kernel(const float* __restrict__ src, _Float16* __restrict__ hi,
                _Float16* __restrict__ lo, int n8) {
  const int stride = gridDim.x * blockDim.x;
  const f32x4* s4 = (const f32x4*)src;
  f16x8* h8 = (f16x8*)hi;
  f16x8* l8 = (f16x8*)lo;
  for (int i = blockIdx.x * blockDim.x + threadIdx.x; i < n8; i += stride) {
    f32x4 v0 = s4[2 * i];
    f32x4 v1 = s4[2 * i + 1];
    f16x8 h, l;
    cvt_split(v0, v1, h, l);
    h8[i] = h;
    l8[i] = l;
  }
}

// global -> LDS staging: linear LDS dest (slot = seg*64 + lane), the unit
// swizzle u_g = u ^ ((row>>1)&3) is applied on the GLOBAL source address
// (rule 21: both-sides-or-neither). Read side applies the same XOR.
#if HAVE_GLDS
#define GL(lbase, g) __builtin_amdgcn_global_load_lds( \
    (const __attribute__((address_space(1))) void*)(g), \
    (__attribute__((address_space(3))) void*)(lbase), 16, 0, 0)
#else
#define GL(lbase, g) (((f16x8*)(lbase))[lane] = *(const f16x8*)(g))
#endif

// BK=32, double-buffered (64 KB LDS), one barrier per K-step,
// stage-next-before-compute (T3-minimum schedule).
__global__ __launch_bounds__(256, 2)
void att_gemm_f(const _Float16* __restrict__ encHi, const _Float16* __restrict__ encLo,
                const _Float16* __restrict__ hidHi, const _Float16* __restrict__ hidLo,
                float* __restrict__ out, float* __restrict__ sums)
{
  // [buf][row*4 + unit] ; 512 f16x8 slots = 8 KB per plane per buffer
  __shared__ f16x8 sAhi[2][512];
  __shared__ f16x8 sAlo[2][512];
  __shared__ f16x8 sBhi[2][512];
  __shared__ f16x8 sBlo[2][512];

  const int tid  = threadIdx.x;
  const int lane = tid & 63;
  const int w    = tid >> 6;
  const int wm   = (w >> 1) << 6;   // wave row offset
  const int wn   = (w & 1) << 6;    // wave col offset

  const int b  = blockIdx.z;
  const int s0 = blockIdx.y * BM;
  const int t0 = blockIdx.x * BN;

  // staging coords: wave w owns segments {2w, 2w+1} of each plane
  // seg = 16 rows x 4 units(16B); lane -> (row = seg*16 + lane>>2, u = lane&3)
  const int rl   = lane >> 2;
  const int uu   = lane & 3;
  const int row0 = w * 32 + rl;
  const int row1 = w * 32 + 16 + rl;
  const int ug0  = uu ^ ((row0 >> 1) & 3);
  const int ug1  = uu ^ ((row1 >> 1) & 3);

  const size_t offA0 = ((size_t)(s0 + row0) * Bn + b) * Hn + ug0 * 8;
  const size_t offA1 = ((size_t)(s0 + row1) * Bn + b) * Hn + ug1 * 8;
  const size_t offB0 = ((size_t)(t0 + row0) * Bn + b) * Hn + ug0 * 8;
  const size_t offB1 = ((size_t)(t0 + row1) * Bn + b) * Hn + ug1 * 8;

  const int slot0 = w * 128;   // seg(2w) base slot; seg(2w+1) = slot0+64

  f32x4 acc[4][4];
#pragma unroll
  for (int m = 0; m < 4; ++m)
#pragma unroll
    for (int n = 0; n < 4; ++n)
      acc[m][n] = (f32x4){0.f, 0.f, 0.f, 0.f};

#define STAGE(bf, ks) do {                                   \
    const size_t ko = (size_t)(ks) * 32;                     \
    GL(&sAhi[bf][slot0],      encHi + offA0 + ko);           \
    GL(&sAhi[bf][slot0 + 64], encHi + offA1 + ko);           \
    GL(&sAlo[bf][slot0],      encLo + offA0 + ko);           \
    GL(&sAlo[bf][slot0 + 64], encLo + offA1 + ko);           \
    GL(&sBhi[bf][slot0],      hidHi + offB0 + ko);           \
    GL(&sBhi[bf][slot0 + 64], hidHi + offB1 + ko);           \
    GL(&sBlo[bf][slot0],      hidLo + offB0 + ko);           \
    GL(&sBlo[bf][slot0 + 64], hidLo + offB1 + ko);           \
  } while (0)

#define COMPUTE(bf) do {                                     \
    const int ko4 = lane >> 4;                               \
    f16x8 ah[4], al[4], bh[4], bl[4];                        \
    _Pragma("unroll")                                        \
    for (int m = 0; m < 4; ++m) {                            \
      const int r  = wm + m * 16 + (lane & 15);              \
      const int us = ko4 ^ ((r >> 1) & 3);                   \
      ah[m] = sAhi[bf][r * 4 + us];                          \
      al[m] = sAlo[bf][r * 4 + us];                          \
    }                                                        \
    _Pragma("unroll")                                        \
    for (int n = 0; n < 4; ++n) {                            \
      const int r  = wn + n * 16 + (lane & 15);              \
      const int us = ko4 ^ ((r >> 1) & 3);                   \
      bh[n] = sBhi[bf][r * 4 + us];                          \
      bl[n] = sBlo[bf][r * 4 + us];                          \
    }                                                        \
    _Pragma("unroll")                                        \
    for (int m = 0; m < 4; ++m)                              \
      _Pragma("unroll")                                      \
      for (int n = 0; n < 4; ++n) {                          \
        acc[m][n] = __builtin_amdgcn_mfma_f32_16x16x32_f16(ah[m], bh[n], acc[m][n], 0, 0, 0); \
        acc[m][n] = __builtin_amdgcn_mfma_f32_16x16x32_f16(ah[m], bl[n], acc[m][n], 0, 0, 0); \
        acc[m][n] = __builtin_amdgcn_mfma_f32_16x16x32_f16(al[m], bh[n], acc[m][n], 0, 0, 0); \
      }                                                      \
  } while (0)

  STAGE(0, 0);
  __syncthreads();

#pragma unroll 1
  for (int ks = 0; ks < 32; ++ks) {
    if (ks < 31) STAGE((ks + 1) & 1, ks + 1);   // prefetch next K-tile
    COMPUTE(ks & 1);
    __syncthreads();                             // drains vmcnt+lgkmcnt
  }

#undef STAGE
#undef COMPUTE

  // epilogue: P = exp(tanh(score)); C/D layout col=lane&15, row=(lane>>4)*4+j
#pragma unroll
  for (int n = 0; n < 4; ++n) {
    const int t = t0 + wn + n * 16 + (lane & 15);
    float csum = 0.f;
#pragma unroll
    for (int m = 0; m < 4; ++m) {
      const int sb = s0 + wm + m * 16 + ((lane >> 4) << 2);
#pragma unroll
      for (int j = 0; j < 4; ++j) {
        const float x = acc[m][n][j];
        const float wgt = __expf(tanhf(x));
        out[((size_t)b * Sn + (sb + j)) * TQn + t] = wgt;
        csum += wgt;
      }
    }
    csum += __shfl_xor(csum, 16, 64);
    csum += __shfl_xor(csum, 32, 64);
    if ((lane >> 4) == 0)
      atomicAdd(&sums[b * TQn + t], csum);
  }
}

// ============================ FALLBACK PATH (verified round 3) ============================

#define BKf 64
#define NKSf (Hn / BKf)

__global__ __launch_bounds__(256, 2)
void att_gemm_fb(const float* __restrict__ hid, const float* __restrict__ enc,
                 float* __restrict__ out, float* __restrict__ sums)
{
  __shared__ f16x8 sAhi[BM * BKf / 8];
  __shared__ f16x8 sAlo[BM * BKf / 8];
  __shared__ f16x8 sBhi[BN * BKf / 8];
  __shared__ f16x8 sBlo[BN * BKf / 8];

  const int tid  = threadIdx.x;
  const int lane = tid & 63;
  const int wv   = tid >> 6;
  const int wm   = (wv >> 1) << 6;
  const int wn   = (wv & 1) << 6;

  const int b  = blockIdx.z;
  const int s0 = blockIdx.y * BM;
  const int t0 = blockIdx.x * BN;

  const int unit = tid & 7;
  const int row0 = tid >> 3;

  const float* encB = enc + (size_t)b * Hn;
  const float* hidB = hid + (size_t)b * Hn;
  const size_t ldg = (size_t)Bn * Hn;

  f32x4 acc[4][4];
#pragma unroll
  for (int m = 0; m < 4; ++m)
#pragma unroll
    for (int n = 0; n < 4; ++n)
      acc[m][n] = (f32x4){0.f, 0.f, 0.f, 0.f};

  f32x4 ra[4][2], rb[4][2];

#pragma unroll
  for (int i = 0; i < 4; ++i) {
    const float* pa = encB + (size_t)(s0 + row0 + 32 * i) * ldg + unit * 8;
    ra[i][0] = *(const f32x4*)pa;
    ra[i][1] = *(const f32x4*)(pa + 4);
    const float* pb = hidB + (size_t)(t0 + row0 + 32 * i) * ldg + unit * 8;
    rb[i][0] = *(const f32x4*)pb;
    rb[i][1] = *(const f32x4*)(pb + 4);
  }
#pragma unroll
  for (int i = 0; i < 4; ++i) {
    const int row = row0 + 32 * i;
    const int u   = unit ^ (row & 7);
    f16x8 hi, lo;
    cvt_split(ra[i][0], ra[i][1], hi, lo);
    sAhi[row * 8 + u] = hi;
    sAlo[row * 8 + u] = lo;
    cvt_split(rb[i][0], rb[i][1], hi, lo);
    sBhi[row * 8 + u] = hi;
    sBlo[row * 8 + u] = lo;
  }
  __syncthreads();

#pragma unroll 1
  for (int ks = 0; ks < NKSf; ++ks) {
    if (ks + 1 < NKSf) {
      const int ko = (ks + 1) * BKf;
#pragma unroll
      for (int i = 0; i < 4; ++i) {
        const float* pa = encB + (size_t)(s0 + row0 + 32 * i) * ldg + ko + unit * 8;
        ra[i][0] = *(const f32x4*)pa;
        ra[i][1] = *(const f32x4*)(pa + 4);
        const float* pb = hidB + (size_t)(t0 + row0 + 32 * i) * ldg + ko + unit * 8;
        rb[i][0] = *(const f32x4*)pb;
        rb[i][1] = *(const f32x4*)(pb + 4);
      }
    }
#pragma unroll
    for (int sl = 0; sl < 2; ++sl) {
      const int ko = sl * 4 + (lane >> 4);
      f16x8 ah[4], al[4], bh[4], bl[4];
#pragma unroll
      for (int m = 0; m < 4; ++m) {
        const int r = wm + m * 16 + (lane & 15);
        const int u = ko ^ (r & 7);
        ah[m] = sAhi[r * 8 + u];
        al[m] = sAlo[r * 8 + u];
      }
#pragma unroll
      for (int n = 0; n < 4; ++n) {
        const int r = wn + n * 16 + (lane & 15);
        const int u = ko ^ (r & 7);
        bh[n] = sBhi[r * 8 + u];
        bl[n] = sBlo[r * 8 + u];
      }
#pragma unroll
      for (int m = 0; m < 4; ++m)
#pragma unroll
        for (int n = 0; n < 4; ++n) {
          acc[m][n] = __builtin_amdgcn_mfma_f32_16x16x32_f16(ah[m], bh[n], acc[m][n], 0, 0, 0);
          acc[m][n] = __builtin_amdgcn_mfma_f32_16x16x32_f16(ah[m], bl[n], acc[m][n], 0, 0, 0);
          acc[m][n] = __builtin_amdgcn_mfma_f32_16x16x32_f16(al[m], bh[n], acc[m][n], 0, 0, 0);
        }
    }
    __syncthreads();

    if (ks + 1 < NKSf) {
#pragma unroll
      for (int i = 0; i < 4; ++i) {
        const int row = row0 + 32 * i;
        const int u   = unit ^ (row & 7);
        f16x8 hi, lo;
        cvt_split(ra[i][0], ra[i][1], hi, lo);
        sAhi[row * 8 + u] = hi;
        sAlo[row * 8 + u] = lo;
        cvt_split(rb[i][0], rb[i][1], hi, lo);
        sBhi[row * 8 + u] = hi;
        sBlo[row * 8 + u] = lo;
      }
    }
    __syncthreads();
  }

#pragma unroll
  for (int n = 0; n < 4; ++n) {
    const int t = t0 + wn + n * 16 + (lane & 15);
    float csum = 0.f;
#pragma unroll
    for (int m = 0; m < 4; ++m) {
      const int sb = s0 + wm + m * 16 + ((lane >> 4) << 2);
#pragma unroll
      for (int j = 0; j < 4; ++j) {
        const float x = acc[m][n][j];
        const float wgt = __expf(tanhf(x));
        out[((size_t)b * Sn + (sb + j)) * TQn + t] = wgt;
        csum += wgt;
      }
    }
    csum += __shfl_xor(csum, 16, 64);
    csum += __shfl_xor(csum, 32, 64);
    if ((lane >> 4) == 0)
      atomicAdd(&sums[b * TQn + t], csum);
  }
}

// ============================ shared small kernels ============================

__global__ void zero_kernel(float* __restrict__ p, int n) {
  int i = blockIdx.x * 256 + threadIdx.x;
  if (i < n) p[i] = 0.f;
}

__global__ void inv_kernel(float* __restrict__ sums, int n) {
  int i = blockIdx.x * 256 + threadIdx.x;
  if (i < n) sums[i] = 1.0f / sums[i];
}

__global__ __launch_bounds__(256)
void scale_kernel(float* __restrict__ out, const float* __restrict__ inv) {
  const int total4 = Bn * Sn * TQn / 4;         // 16,777,216
  f32x4* o4 = (f32x4*)out;
  const f32x4* i4 = (const f32x4*)inv;
  const int stride = gridDim.x * blockDim.x;
  for (int i = blockIdx.x * blockDim.x + threadIdx.x; i < total4; i += stride) {
    const int tq = i & 255;          // TQ/4 = 256
    const int bb = i >> 20;          // / (S*TQ/4)
    f32x4 v = o4[i];
    f32x4 s = i4[bb * 256 + tq];
    o4[i] = v * s;
  }
}

// ============================ launch ============================

extern "C" void kernel_launch(void* const* d_in, const int* in_sizes, int n_in,
                              void* d_out, int out_size, void* d_ws, size_t ws_size,
                              hipStream_t stream) {
  const float* hid = (const float*)d_in[0];   // hiddenState [TQ,B,H]
  const float* enc = (const float*)d_in[1];   // encoderOut  [S,B,H]
  float* out = (float*)d_out;                 // [B,S,TQ]

  const size_t ENC_N = (size_t)Sn * Bn * Hn;  // 67,108,864
  const size_t HID_N = (size_t)TQn * Bn * Hn; // 16,777,216
  const size_t need  = (ENC_N + HID_N) * 4 + 65536;   // hi+lo f16 + sums

  const int nsum = Bn * TQn;                  // 16384
  dim3 grid(TQn / BN, Sn / BM, Bn);           // (8, 32, 16)

  if (ws_size >= need) {
    _Float16* encHi = (_Float16*)d_ws;
    _Float16* encLo = encHi + ENC_N;
    _Float16* hidHi = encLo + ENC_N;
    _Float16* hidLo = hidHi + HID_N;
    float* sums = (float*)(hidLo + HID_N);

    zero_kernel<<<(nsum + 255) / 256, 256, 0, stream>>>(sums, nsum);
    cvt_kernel<<<2048, 256, 0, stream>>>(enc, encHi, encLo, (int)(ENC_N / 8));
    cvt_kernel<<<2048, 256, 0, stream>>>(hid, hidHi, hidLo, (int)(HID_N / 8));
    att_gemm_f<<<grid, 256, 0, stream>>>(encHi, encLo, hidHi, hidLo, out, sums);
    inv_kernel<<<(nsum + 255) / 256, 256, 0, stream>>>(sums, nsum);
    scale_kernel<<<2048, 256, 0, stream>>>(out, sums);
  } else {
    float* sums = (float*)d_ws;
    zero_kernel<<<(nsum + 255) / 256, 256, 0, stream>>>(sums, nsum);
    att_gemm_fb<<<grid, 256, 0, stream>>>(hid, enc, out, sums);
    inv_kernel<<<(nsum + 255) / 256, 256, 0, stream>>>(sums, nsum);
    scale_kernel<<<2048, 256, 0, stream>>>(out, sums);
  }
}